// Round 7
// baseline (3314.011 us; speedup 1.0000x reference)
//
#include <hip/hip_runtime.h>
#include <hip/hip_cooperative_groups.h>
#include <math.h>
#include <float.h>

namespace cg = cooperative_groups;

#define LEVEL_W 512
#define DEPTH   16
#define NNODES  8192
#define DIN     512
#define HD      512
#define ED      200
#define NC      150
#define GDIM    2048
#define OUTROWS 7680
#define KH      512        // f-buffer K (features), also h K
#define KW      1024       // combined weight K: [Wh(0:512) | Wx(512:1024)]
#define NKC     16         // K-chunks of 64 over KW

typedef __attribute__((ext_vector_type(8))) short s8v;   // 8 bf16 (4 VGPRs)
typedef __attribute__((ext_vector_type(4))) float f4v;   // 4 fp32 acc

__device__ __forceinline__ unsigned short f2bf(float x) {
    unsigned int u = __float_as_uint(x);
    u += 0x7FFFu + ((u >> 16) & 1u);
    return (unsigned short)(u >> 16);
}
__device__ __forceinline__ float bf2f(unsigned short b) {
    return __uint_as_float(((unsigned int)b) << 16);
}
__device__ __forceinline__ float sigm(float x) { return 1.0f / (1.0f + expf(-x)); }

__device__ __forceinline__ void gl_lds16(const void* g, void* l) {
    __builtin_amdgcn_global_load_lds((const __attribute__((address_space(1))) void*)g,
                                     (__attribute__((address_space(3))) void*)l, 16, 0, 0);
}

// ---------------------------------------------------------------------------
// prep_w: combined W^T [2048 n''][1024 k] as bf16 hi/lo.
// n'' = hcs*64 + gate*16 + hcl  <->  orig col = gate*512 + hcs*16 + hcl.
// k 0..511 = Wh rows, k 512..1023 = Wx rows 0..511 (features part).
// 16B chunks XOR-swizzled within each 128B window (key = n'' & 7).
// ---------------------------------------------------------------------------
__global__ __launch_bounds__(256) void prep_w(
    const float* __restrict__ Wx, const float* __restrict__ Wh,
    unsigned short* __restrict__ w_hi, unsigned short* __restrict__ w_lo)
{
    __shared__ float Wt[64][65];
    const int t   = threadIdx.x;
    const int b   = blockIdx.x;
    const int mat = b >> 5;             // 0 = Wh (k 0..511), 1 = Wx (k 512..1023)
    const int ns  = b & 31;
    const float* src = mat ? Wx : Wh;

    for (int kw = 0; kw < 8; ++kw) {
        __syncthreads();
        #pragma unroll
        for (int p = 0; p < 16; ++p) {
            int gl  = p >> 2;
            int kk  = (p & 3) * 16 + (t >> 4);
            int col = gl * 512 + ns * 16 + (t & 15);
            Wt[kk][gl * 16 + (t & 15)] = src[(size_t)(kw * 64 + kk) * GDIM + col];
        }
        __syncthreads();
        {
            int nl  = t >> 2;
            int cp  = t & 3;
            int nsg = ns * 64 + nl;
            int key = nsg & 7;
            __align__(16) unsigned short hv[16], lv[16];
            #pragma unroll
            for (int e = 0; e < 16; ++e) {
                float x = Wt[cp * 16 + e][nl];
                unsigned short h = f2bf(x);
                hv[e] = h;
                lv[e] = f2bf(x - bf2f(h));
            }
            size_t base = (size_t)nsg * KW + mat * 512 + kw * 64;
            int c0 = cp * 2, c1 = cp * 2 + 1;
            *(uint4*)&w_hi[base + ((c0 ^ key) * 8)] = *(const uint4*)&hv[0];
            *(uint4*)&w_hi[base + ((c1 ^ key) * 8)] = *(const uint4*)&hv[8];
            *(uint4*)&w_lo[base + ((c0 ^ key) * 8)] = *(const uint4*)&lv[0];
            *(uint4*)&w_lo[base + ((c1 ^ key) * 8)] = *(const uint4*)&lv[8];
        }
    }
}

// ---------------------------------------------------------------------------
// prep_feat: features -> f_hi/f_lo bf16 [8192][512], chunk-swizzled (key r&7);
// also inv[order[i]] = i.
// ---------------------------------------------------------------------------
__global__ __launch_bounds__(256) void prep_feat(
    const float* __restrict__ features, const int* __restrict__ order,
    unsigned short* __restrict__ f_hi, unsigned short* __restrict__ f_lo,
    int* __restrict__ inv)
{
    int i = blockIdx.x * 256 + threadIdx.x;      // 262144 threads
    {
        int r  = i >> 5;
        int k0 = (i & 31) * 16;
        const float* srcp = features + (size_t)r * DIN + k0;
        __align__(16) unsigned short hv[16], lv[16];
        #pragma unroll
        for (int e = 0; e < 16; ++e) {
            float x = srcp[e];
            unsigned short h = f2bf(x);
            hv[e] = h;
            lv[e] = f2bf(x - bf2f(h));
        }
        int key = r & 7;
        int c0  = (k0 >> 3) & 7;
        size_t base = (size_t)r * KH + (k0 & ~63);
        *(uint4*)&f_hi[base + ((c0 ^ key) * 8)]       = *(const uint4*)&hv[0];
        *(uint4*)&f_hi[base + (((c0 + 1) ^ key) * 8)] = *(const uint4*)&hv[8];
        *(uint4*)&f_lo[base + ((c0 ^ key) * 8)]       = *(const uint4*)&lv[0];
        *(uint4*)&f_lo[base + (((c0 + 1) ^ key) * 8)] = *(const uint4*)&lv[8];
    }
    if (i < NNODES) inv[order[i]] = i;
}

// ---------------------------------------------------------------------------
// prep_embed: g_embed[e][n''] = embed[e]·Wx[512:712][orig(n'')] + b[orig(n'')]
// ---------------------------------------------------------------------------
__global__ __launch_bounds__(128) void prep_embed(
    const float* __restrict__ embed, const float* __restrict__ Wx,
    const float* __restrict__ bvec, float* __restrict__ g_embed)
{
    int e    = blockIdx.y;
    int np   = blockIdx.x * 128 + threadIdx.x;
    int gate = (np >> 4) & 3, hcs = np >> 6, hcl = np & 15;
    int col  = gate * 512 + hcs * 16 + hcl;
    float acc = bvec[col];
    const float* er = embed + (size_t)e * ED;
    for (int k = 0; k < ED; ++k)
        acc += er[k] * Wx[(size_t)(DIN + k) * GDIM + col];
    g_embed[(size_t)e * GDIM + np] = acc;
}

// ===========================================================================
// forest_kernel: persistent cooperative kernel — all 16 levels in one launch.
// 512 blocks x 128 threads (2 blocks/CU by LDS/VGPR arithmetic).
// Per level: phase G (gemm+cell, body identical to round-5 gemm_h_cell with
// ns=bid&31, mt=bid>>5) -> grid.sync -> phase D (dist+argmax, 1 row/block)
// -> grid.sync.
// ===========================================================================
__global__ __launch_bounds__(128) void forest_kernel(
    float* h_all, float* c_all,
    const int* __restrict__ parent, int* __restrict__ cm_all,
    const unsigned short* __restrict__ w_hi, const unsigned short* __restrict__ w_lo,
    const unsigned short* __restrict__ f_hi, const unsigned short* __restrict__ f_lo,
    const float* __restrict__ g_embed, const float* __restrict__ dropout,
    const float* __restrict__ outW, const float* __restrict__ outb,
    const int* __restrict__ inv, float* __restrict__ d_out)
{
    cg::grid_group grid = cg::this_grid();

    __shared__ unsigned short Ah[32 * 64], Al[32 * 64], Bh[64 * 64], Bl[64 * 64];
    __shared__ int p_s[32], rt_s[32], ei_s[32];
    __shared__ float h_s[512];
    __shared__ float dist_s[160];

    const int t = threadIdx.x, w = t >> 6, lane = t & 63;
    const int bid = blockIdx.x;
    const int ns = bid & 31, mt = bid >> 5;

    for (int l = 0; l < DEPTH; ++l) {
        const int off = l * LEVEL_W;
        // ================= phase G: gemm + LSTM cell =================
        {
            const int grow0 = off + mt * 32;

            if (t < 32) {
                int p  = parent[grow0 + t];
                int rt = (p < 0) ? 1 : 0;
                p_s[t]  = rt ? 0 : p;
                rt_s[t] = rt;
                ei_s[t] = rt ? 0 : (cm_all[rt ? 0 : p] + 1);
            }
            __syncthreads();

            f4v acc[4];
            #pragma unroll
            for (int i = 0; i < 4; ++i) acc[i] = (f4v){0.f, 0.f, 0.f, 0.f};

            const int ar  = t >> 2;            // 0..31 (A gather row)
            const int aq  = t & 3;             // quarter of the 64-elem window
            const int ap  = p_s[ar];
            const int art = rt_s[ar];
            const float* asrc = h_all + (size_t)ap * HD + aq * 16;
            const int akey = ar & 7;
            const int ac0  = aq * 2;

            for (int kc = 0; kc < NKC; ++kc) {
                if (kc < 8) {
                    float x[16];
                    if (art) {
                        #pragma unroll
                        for (int e = 0; e < 16; ++e) x[e] = 0.f;
                    } else {
                        const float4* s4 = (const float4*)(asrc + kc * 64);
                        float4 v0 = s4[0], v1 = s4[1], v2 = s4[2], v3 = s4[3];
                        x[0] = v0.x; x[1] = v0.y; x[2] = v0.z; x[3] = v0.w;
                        x[4] = v1.x; x[5] = v1.y; x[6] = v1.z; x[7] = v1.w;
                        x[8] = v2.x; x[9] = v2.y; x[10] = v2.z; x[11] = v2.w;
                        x[12] = v3.x; x[13] = v3.y; x[14] = v3.z; x[15] = v3.w;
                    }
                    __align__(16) unsigned short hv[16], lv[16];
                    #pragma unroll
                    for (int e = 0; e < 16; ++e) {
                        unsigned short h = f2bf(x[e]);
                        hv[e] = h;
                        lv[e] = f2bf(x[e] - bf2f(h));
                    }
                    *(uint4*)&Ah[ar * 64 + ((ac0 ^ akey) * 8)]       = *(const uint4*)&hv[0];
                    *(uint4*)&Ah[ar * 64 + (((ac0 + 1) ^ akey) * 8)] = *(const uint4*)&hv[8];
                    *(uint4*)&Al[ar * 64 + ((ac0 ^ akey) * 8)]       = *(const uint4*)&lv[0];
                    *(uint4*)&Al[ar * 64 + (((ac0 + 1) ^ akey) * 8)] = *(const uint4*)&lv[8];
                } else {
                    #pragma unroll
                    for (int q = 0; q < 2; ++q) {
                        int ia  = w * 2 + q;                       // 0..3, wave-uniform
                        int row = ia * 8 + (lane >> 3);            // 0..31
                        size_t aoff = ((size_t)(grow0 + row) * KH + (kc - 8) * 64) * 2
                                      + (lane & 7) * 16;
                        gl_lds16((const char*)f_hi + aoff, (char*)Ah + ia * 1024);
                        gl_lds16((const char*)f_lo + aoff, (char*)Al + ia * 1024);
                    }
                }
                #pragma unroll
                for (int q = 0; q < 4; ++q) {
                    int ib  = w * 4 + q;                           // 0..7, wave-uniform
                    int row = ib * 8 + (lane >> 3);                // 0..63
                    size_t boff = ((size_t)(ns * 64 + row) * KW + kc * 64) * 2
                                  + (lane & 7) * 16;
                    gl_lds16((const char*)w_hi + boff, (char*)Bh + ib * 1024);
                    gl_lds16((const char*)w_lo + boff, (char*)Bl + ib * 1024);
                }
                __syncthreads();
                #pragma unroll
                for (int s = 0; s < 2; ++s) {
                    int arow = w * 16 + (lane & 15);
                    int ach  = s * 4 + (lane >> 4);
                    s8v ahv = *(const s8v*)&Ah[arow * 64 + ((ach ^ (arow & 7)) * 8)];
                    s8v alv = *(const s8v*)&Al[arow * 64 + ((ach ^ (arow & 7)) * 8)];
                    #pragma unroll
                    for (int fn = 0; fn < 4; ++fn) {
                        int brow = fn * 16 + (lane & 15);
                        s8v bhv = *(const s8v*)&Bh[brow * 64 + ((ach ^ (brow & 7)) * 8)];
                        s8v blv = *(const s8v*)&Bl[brow * 64 + ((ach ^ (brow & 7)) * 8)];
                        acc[fn] = __builtin_amdgcn_mfma_f32_16x16x32_bf16(ahv, bhv, acc[fn], 0, 0, 0);
                        acc[fn] = __builtin_amdgcn_mfma_f32_16x16x32_bf16(ahv, blv, acc[fn], 0, 0, 0);
                        acc[fn] = __builtin_amdgcn_mfma_f32_16x16x32_bf16(alv, bhv, acc[fn], 0, 0, 0);
                    }
                }
                __syncthreads();
            }

            const int hcl  = lane & 15;
            const int hcol = ns * 16 + hcl;
            const float dm = dropout[hcol];
            #pragma unroll
            for (int j = 0; j < 4; ++j) {
                int lr   = w * 16 + (lane >> 4) * 4 + j;
                int grow = grow0 + lr;
                const float* gep = g_embed + (size_t)ei_s[lr] * GDIM + ns * 64;
                float gi = acc[0][j] + gep[0 * 16 + hcl];
                float gf = acc[1][j] + gep[1 * 16 + hcl];
                float gg = acc[2][j] + gep[2 * 16 + hcl];
                float go = acc[3][j] + gep[3 * 16 + hcl];
                float cpar = rt_s[lr] ? 0.f : c_all[(size_t)p_s[lr] * HD + hcol];
                float c2 = sigm(gf) * cpar + sigm(gi) * tanhf(gg);
                float h2 = sigm(go) * tanhf(c2) * dm;
                c_all[(size_t)grow * HD + hcol] = c2;
                h_all[(size_t)grow * HD + hcol] = h2;
            }
        }
        __threadfence();
        grid.sync();

        // ================= phase D: dist + argmax (1 row per block) ==
        {
            const int grow = off + bid;
            const float* hrow = h_all + (size_t)grow * HD;
            *(float4*)&h_s[t * 4] = ((const float4*)hrow)[t];
            __syncthreads();

            const int j  = t;
            const int j2 = t + 128;
            if (j < NC) {
                float a = 0.f;
                #pragma unroll 8
                for (int k = 0; k < HD; ++k) a += h_s[k] * outW[k * NC + j];
                dist_s[j] = a + outb[j];
            }
            if (j2 < NC) {
                float a = 0.f;
                #pragma unroll 8
                for (int k = 0; k < HD; ++k) a += h_s[k] * outW[k * NC + j2];
                dist_s[j2] = a + outb[j2];
            }
            __syncthreads();

            const int orow = inv[grow];
            if (orow < OUTROWS) {
                if (j < NC)  d_out[(size_t)orow * NC + j]  = dist_s[j];
                if (j2 < NC) d_out[(size_t)orow * NC + j2] = dist_s[j2];
            }

            if (t < 64) {
                float best = -FLT_MAX;
                int   bidx = 0x7fffffff;
                for (int jj = t; jj < NC; jj += 64) {
                    float v = dist_s[jj];
                    if (v > best || (v == best && jj < bidx)) { best = v; bidx = jj; }
                }
                #pragma unroll
                for (int m = 32; m >= 1; m >>= 1) {
                    float ov = __shfl_xor(best, m);
                    int   oi = __shfl_xor(bidx, m);
                    if (ov > best || (ov == best && oi < bidx)) { best = ov; bidx = oi; }
                }
                if (t == 0) {
                    cm_all[grow] = bidx;
                    if (orow < OUTROWS) d_out[(size_t)OUTROWS * NC + orow] = (float)bidx;
                }
            }
            __syncthreads();
        }
        __threadfence();
        grid.sync();
    }
}

// ---------------------------------------------------------------------------
// Fallback per-level kernels (identical to the passing round-5 versions);
// used only if the cooperative launch is rejected.
// ---------------------------------------------------------------------------
__global__ __launch_bounds__(128) void gemm_h_cell(
    float* h_all, float* c_all,
    const int* __restrict__ parent, const int* __restrict__ cm_all,
    const unsigned short* __restrict__ w_hi, const unsigned short* __restrict__ w_lo,
    const unsigned short* __restrict__ f_hi, const unsigned short* __restrict__ f_lo,
    const float* __restrict__ g_embed, const float* __restrict__ dropout, int off)
{
    __shared__ unsigned short Ah[32 * 64], Al[32 * 64], Bh[64 * 64], Bl[64 * 64];
    __shared__ int p_s[32], rt_s[32], ei_s[32];
    const int t = threadIdx.x, w = t >> 6, lane = t & 63;
    const int ns = blockIdx.x, mt = blockIdx.y;
    const int grow0 = off + mt * 32;

    if (t < 32) {
        int p  = parent[grow0 + t];
        int rt = (p < 0) ? 1 : 0;
        p_s[t]  = rt ? 0 : p;
        rt_s[t] = rt;
        ei_s[t] = rt ? 0 : (cm_all[rt ? 0 : p] + 1);
    }
    __syncthreads();

    f4v acc[4];
    #pragma unroll
    for (int i = 0; i < 4; ++i) acc[i] = (f4v){0.f, 0.f, 0.f, 0.f};

    const int ar  = t >> 2;
    const int aq  = t & 3;
    const int ap  = p_s[ar];
    const int art = rt_s[ar];
    const float* asrc = h_all + (size_t)ap * HD + aq * 16;
    const int akey = ar & 7;
    const int ac0  = aq * 2;

    for (int kc = 0; kc < NKC; ++kc) {
        if (kc < 8) {
            float x[16];
            if (art) {
                #pragma unroll
                for (int e = 0; e < 16; ++e) x[e] = 0.f;
            } else {
                const float4* s4 = (const float4*)(asrc + kc * 64);
                float4 v0 = s4[0], v1 = s4[1], v2 = s4[2], v3 = s4[3];
                x[0] = v0.x; x[1] = v0.y; x[2] = v0.z; x[3] = v0.w;
                x[4] = v1.x; x[5] = v1.y; x[6] = v1.z; x[7] = v1.w;
                x[8] = v2.x; x[9] = v2.y; x[10] = v2.z; x[11] = v2.w;
                x[12] = v3.x; x[13] = v3.y; x[14] = v3.z; x[15] = v3.w;
            }
            __align__(16) unsigned short hv[16], lv[16];
            #pragma unroll
            for (int e = 0; e < 16; ++e) {
                unsigned short h = f2bf(x[e]);
                hv[e] = h;
                lv[e] = f2bf(x[e] - bf2f(h));
            }
            *(uint4*)&Ah[ar * 64 + ((ac0 ^ akey) * 8)]       = *(const uint4*)&hv[0];
            *(uint4*)&Ah[ar * 64 + (((ac0 + 1) ^ akey) * 8)] = *(const uint4*)&hv[8];
            *(uint4*)&Al[ar * 64 + ((ac0 ^ akey) * 8)]       = *(const uint4*)&lv[0];
            *(uint4*)&Al[ar * 64 + (((ac0 + 1) ^ akey) * 8)] = *(const uint4*)&lv[8];
        } else {
            #pragma unroll
            for (int q = 0; q < 2; ++q) {
                int ia  = w * 2 + q;
                int row = ia * 8 + (lane >> 3);
                size_t aoff = ((size_t)(grow0 + row) * KH + (kc - 8) * 64) * 2
                              + (lane & 7) * 16;
                gl_lds16((const char*)f_hi + aoff, (char*)Ah + ia * 1024);
                gl_lds16((const char*)f_lo + aoff, (char*)Al + ia * 1024);
            }
        }
        #pragma unroll
        for (int q = 0; q < 4; ++q) {
            int ib  = w * 4 + q;
            int row = ib * 8 + (lane >> 3);
            size_t boff = ((size_t)(ns * 64 + row) * KW + kc * 64) * 2
                          + (lane & 7) * 16;
            gl_lds16((const char*)w_hi + boff, (char*)Bh + ib * 1024);
            gl_lds16((const char*)w_lo + boff, (char*)Bl + ib * 1024);
        }
        __syncthreads();
        #pragma unroll
        for (int s = 0; s < 2; ++s) {
            int arow = w * 16 + (lane & 15);
            int ach  = s * 4 + (lane >> 4);
            s8v ahv = *(const s8v*)&Ah[arow * 64 + ((ach ^ (arow & 7)) * 8)];
            s8v alv = *(const s8v*)&Al[arow * 64 + ((ach ^ (arow & 7)) * 8)];
            #pragma unroll
            for (int fn = 0; fn < 4; ++fn) {
                int brow = fn * 16 + (lane & 15);
                s8v bhv = *(const s8v*)&Bh[brow * 64 + ((ach ^ (brow & 7)) * 8)];
                s8v blv = *(const s8v*)&Bl[brow * 64 + ((ach ^ (brow & 7)) * 8)];
                acc[fn] = __builtin_amdgcn_mfma_f32_16x16x32_bf16(ahv, bhv, acc[fn], 0, 0, 0);
                acc[fn] = __builtin_amdgcn_mfma_f32_16x16x32_bf16(ahv, blv, acc[fn], 0, 0, 0);
                acc[fn] = __builtin_amdgcn_mfma_f32_16x16x32_bf16(alv, bhv, acc[fn], 0, 0, 0);
            }
        }
        __syncthreads();
    }

    const int hcl  = lane & 15;
    const int hcol = ns * 16 + hcl;
    const float dm = dropout[hcol];
    #pragma unroll
    for (int j = 0; j < 4; ++j) {
        int lr   = w * 16 + (lane >> 4) * 4 + j;
        int grow = grow0 + lr;
        const float* gep = g_embed + (size_t)ei_s[lr] * GDIM + ns * 64;
        float gi = acc[0][j] + gep[0 * 16 + hcl];
        float gf = acc[1][j] + gep[1 * 16 + hcl];
        float gg = acc[2][j] + gep[2 * 16 + hcl];
        float go = acc[3][j] + gep[3 * 16 + hcl];
        float cpar = rt_s[lr] ? 0.f : c_all[(size_t)p_s[lr] * HD + hcol];
        float c2 = sigm(gf) * cpar + sigm(gi) * tanhf(gg);
        float h2 = sigm(go) * tanhf(c2) * dm;
        c_all[(size_t)grow * HD + hcol] = c2;
        h_all[(size_t)grow * HD + hcol] = h2;
    }
}

__global__ __launch_bounds__(256) void level_dist(
    const float* __restrict__ h_all, const float* __restrict__ outW,
    const float* __restrict__ outb, const int* __restrict__ inv,
    float* __restrict__ d_out, int* __restrict__ cm_all, int off)
{
    __shared__ float h_s[4][512];
    __shared__ float dist_s[4][160];

    const int tid = threadIdx.x;
    const int r0  = blockIdx.x * 4;

    for (int i4 = tid; i4 < 512; i4 += 256) {
        int row = i4 >> 7;
        int k   = (i4 & 127) * 4;
        *(float4*)&h_s[row][k] =
            *(const float4*)&h_all[(size_t)(off + r0 + row) * HD + k];
    }
    __syncthreads();

    const int j = tid;
    if (j < NC) {
        float a0 = 0.f, a1 = 0.f, a2 = 0.f, a3 = 0.f;
        for (int k = 0; k < HD; ++k) {
            float w = outW[k * NC + j];
            a0 += h_s[0][k] * w;
            a1 += h_s[1][k] * w;
            a2 += h_s[2][k] * w;
            a3 += h_s[3][k] * w;
        }
        float bj = outb[j];
        dist_s[0][j] = a0 + bj;
        dist_s[1][j] = a1 + bj;
        dist_s[2][j] = a2 + bj;
        dist_s[3][j] = a3 + bj;
    }
    __syncthreads();

    if (j < NC) {
        #pragma unroll
        for (int r = 0; r < 4; ++r) {
            int orow = inv[off + r0 + r];
            if (orow < OUTROWS) d_out[(size_t)orow * NC + j] = dist_s[r][j];
        }
    }

    const int r    = tid >> 6;
    const int lane = tid & 63;
    float best = -3.402823466e38f;
    int   bidx = 0x7fffffff;
    for (int jj = lane; jj < NC; jj += 64) {
        float v = dist_s[r][jj];
        if (v > best || (v == best && jj < bidx)) { best = v; bidx = jj; }
    }
    #pragma unroll
    for (int m = 32; m >= 1; m >>= 1) {
        float ov = __shfl_xor(best, m);
        int   oi = __shfl_xor(bidx, m);
        if (ov > best || (ov == best && oi < bidx)) { best = ov; bidx = oi; }
    }
    if (lane == 0) {
        int grow = off + r0 + r;
        cm_all[grow] = bidx;
        int orow = inv[grow];
        if (orow < OUTROWS) d_out[(size_t)OUTROWS * NC + orow] = (float)bidx;
    }
}

// ---------------------------------------------------------------------------
extern "C" void kernel_launch(void* const* d_in, const int* in_sizes, int n_in,
                              void* d_out, int out_size, void* d_ws, size_t ws_size,
                              hipStream_t stream)
{
    const float* features = (const float*)d_in[0];
    const float* embed    = (const float*)d_in[1];
    const float* Wx       = (const float*)d_in[2];
    const float* Wh       = (const float*)d_in[3];
    const float* bias     = (const float*)d_in[4];
    const float* outW     = (const float*)d_in[5];
    const float* outb     = (const float*)d_in[6];
    const float* dropout  = (const float*)d_in[7];
    const int*   parent   = (const int*)d_in[8];
    const int*   order    = (const int*)d_in[9];

    char* p = (char*)d_ws;
    unsigned short* w_hi   = (unsigned short*)p; p += (size_t)GDIM * KW * 2;   // 4MB
    unsigned short* w_lo   = (unsigned short*)p; p += (size_t)GDIM * KW * 2;   // 4MB
    unsigned short* f_hi   = (unsigned short*)p; p += (size_t)NNODES * KH * 2; // 8MB
    unsigned short* f_lo   = (unsigned short*)p; p += (size_t)NNODES * KH * 2; // 8MB
    float*          g_emb  = (float*)p;          p += (size_t)(NC + 2) * GDIM * 4;
    float*          h_all  = (float*)p;          p += (size_t)NNODES * HD * 4; // 16.8MB
    float*          c_all  = (float*)p;          p += (size_t)NNODES * HD * 4; // 16.8MB
    int*            cm_all = (int*)p;            p += (size_t)NNODES * 4;
    int*            inv    = (int*)p;            p += (size_t)NNODES * 4;

    float* out = (float*)d_out;

    prep_w<<<64, 256, 0, stream>>>(Wx, Wh, w_hi, w_lo);
    prep_feat<<<1024, 256, 0, stream>>>(features, order, f_hi, f_lo, inv);
    prep_embed<<<dim3(16, NC + 1), 128, 0, stream>>>(embed, Wx, bias, g_emb);

    void* args[] = {
        (void*)&h_all, (void*)&c_all, (void*)&parent, (void*)&cm_all,
        (void*)&w_hi, (void*)&w_lo, (void*)&f_hi, (void*)&f_lo,
        (void*)&g_emb, (void*)&dropout, (void*)&outW, (void*)&outb,
        (void*)&inv, (void*)&out
    };
    hipError_t err = hipLaunchCooperativeKernel(
        (const void*)forest_kernel, dim3(512), dim3(128), args, 0, stream);

    if (err != hipSuccess) {
        // Fallback: proven 32-launch path
        for (int l = 0; l < DEPTH; ++l) {
            int off = l * LEVEL_W;
            gemm_h_cell<<<dim3(32, 16), 128, 0, stream>>>(
                h_all, c_all, parent, cm_all, w_hi, w_lo, f_hi, f_lo, g_emb, dropout, off);
            level_dist<<<128, 256, 0, stream>>>(
                h_all, outW, outb, inv, out, cm_all, off);
        }
    }
}

// Round 8
// 2366.105 us; speedup vs baseline: 1.4006x; 1.4006x over previous
//
#include <hip/hip_runtime.h>
#include <math.h>
#include <float.h>

#define LEVEL_W 512
#define DEPTH   16
#define NNODES  8192
#define DIN     512
#define HD      512
#define ED      200
#define NC      150
#define GDIM    2048
#define OUTROWS 7680
#define KH      512        // f-buffer K (features), also h K
#define KW      1024       // combined weight K: [Wh(0:512) | Wx(512:1024)]
#define NKC     16         // K-chunks of 64 over KW
#define NBLK    512        // forest_kernel grid
#define BSUB    8          // barrier sub-counters

typedef __attribute__((ext_vector_type(8))) short s8v;   // 8 bf16 (4 VGPRs)
typedef __attribute__((ext_vector_type(4))) float f4v;   // 4 fp32 acc

__device__ __forceinline__ unsigned short f2bf(float x) {
    unsigned int u = __float_as_uint(x);
    u += 0x7FFFu + ((u >> 16) & 1u);
    return (unsigned short)(u >> 16);
}
__device__ __forceinline__ float bf2f(unsigned short b) {
    return __uint_as_float(((unsigned int)b) << 16);
}
__device__ __forceinline__ float sigm(float x) { return 1.0f / (1.0f + expf(-x)); }

__device__ __forceinline__ void gl_lds16(const void* g, void* l) {
    __builtin_amdgcn_global_load_lds((const __attribute__((address_space(1))) void*)g,
                                     (__attribute__((address_space(3))) void*)l, 16, 0, 0);
}

// ---------------------------------------------------------------------------
// Hand-rolled grid barrier: 2-level arrive (8 sub-counters -> master -> gen),
// agent-scope atomics in d_ws, acquire-spin with s_sleep.  ~2-3 us expected
// vs ~85 us measured for cg::grid_group::sync() (round-7 counters).
// Layout (units of unsigned, 64B apart): sub[i]=bar[i*16], master=bar[128],
// gen=bar[144].  Zeroed by prep_feat each call.
// ---------------------------------------------------------------------------
__device__ __forceinline__ void grid_barrier(unsigned* bar) {
    __syncthreads();
    if (threadIdx.x == 0) {
        __threadfence();   // release this block's global writes (device scope)
        unsigned* sub    = bar + (blockIdx.x & (BSUB - 1)) * 16;
        unsigned* master = bar + BSUB * 16;
        unsigned* gen    = bar + (BSUB + 1) * 16;
        unsigned g = __hip_atomic_load(gen, __ATOMIC_RELAXED, __HIP_MEMORY_SCOPE_AGENT);
        unsigned v = __hip_atomic_fetch_add(sub, 1u, __ATOMIC_ACQ_REL, __HIP_MEMORY_SCOPE_AGENT);
        if (v == (NBLK / BSUB) - 1) {
            unsigned m = __hip_atomic_fetch_add(master, 1u, __ATOMIC_ACQ_REL, __HIP_MEMORY_SCOPE_AGENT);
            if (m == BSUB - 1) {
                #pragma unroll
                for (int i = 0; i < BSUB; ++i)
                    __hip_atomic_store(bar + i * 16, 0u, __ATOMIC_RELAXED, __HIP_MEMORY_SCOPE_AGENT);
                __hip_atomic_store(master, 0u, __ATOMIC_RELAXED, __HIP_MEMORY_SCOPE_AGENT);
                __hip_atomic_store(gen, g + 1u, __ATOMIC_RELEASE, __HIP_MEMORY_SCOPE_AGENT);
            }
        }
        while (__hip_atomic_load(gen, __ATOMIC_ACQUIRE, __HIP_MEMORY_SCOPE_AGENT) == g)
            __builtin_amdgcn_s_sleep(2);
        __threadfence();   // acquire side: see other blocks' writes
    }
    __syncthreads();
}

// ---------------------------------------------------------------------------
// prep_w: combined W^T [2048 n''][1024 k] as bf16 hi/lo.
// n'' = hcs*64 + gate*16 + hcl  <->  orig col = gate*512 + hcs*16 + hcl.
// k 0..511 = Wh rows, k 512..1023 = Wx rows 0..511 (features part).
// 16B chunks XOR-swizzled within each 128B window (key = n'' & 7).
// ---------------------------------------------------------------------------
__global__ __launch_bounds__(256) void prep_w(
    const float* __restrict__ Wx, const float* __restrict__ Wh,
    unsigned short* __restrict__ w_hi, unsigned short* __restrict__ w_lo)
{
    __shared__ float Wt[64][65];
    const int t   = threadIdx.x;
    const int b   = blockIdx.x;
    const int mat = b >> 5;             // 0 = Wh (k 0..511), 1 = Wx (k 512..1023)
    const int ns  = b & 31;
    const float* src = mat ? Wx : Wh;

    for (int kw = 0; kw < 8; ++kw) {
        __syncthreads();
        #pragma unroll
        for (int p = 0; p < 16; ++p) {
            int gl  = p >> 2;
            int kk  = (p & 3) * 16 + (t >> 4);
            int col = gl * 512 + ns * 16 + (t & 15);
            Wt[kk][gl * 16 + (t & 15)] = src[(size_t)(kw * 64 + kk) * GDIM + col];
        }
        __syncthreads();
        {
            int nl  = t >> 2;
            int cp  = t & 3;
            int nsg = ns * 64 + nl;
            int key = nsg & 7;
            __align__(16) unsigned short hv[16], lv[16];
            #pragma unroll
            for (int e = 0; e < 16; ++e) {
                float x = Wt[cp * 16 + e][nl];
                unsigned short h = f2bf(x);
                hv[e] = h;
                lv[e] = f2bf(x - bf2f(h));
            }
            size_t base = (size_t)nsg * KW + mat * 512 + kw * 64;
            int c0 = cp * 2, c1 = cp * 2 + 1;
            *(uint4*)&w_hi[base + ((c0 ^ key) * 8)] = *(const uint4*)&hv[0];
            *(uint4*)&w_hi[base + ((c1 ^ key) * 8)] = *(const uint4*)&hv[8];
            *(uint4*)&w_lo[base + ((c0 ^ key) * 8)] = *(const uint4*)&lv[0];
            *(uint4*)&w_lo[base + ((c1 ^ key) * 8)] = *(const uint4*)&lv[8];
        }
    }
}

// ---------------------------------------------------------------------------
// prep_feat: features -> f_hi/f_lo bf16 [8192][512], chunk-swizzled (key r&7);
// inv[order[i]] = i; zero the barrier state.
// ---------------------------------------------------------------------------
__global__ __launch_bounds__(256) void prep_feat(
    const float* __restrict__ features, const int* __restrict__ order,
    unsigned short* __restrict__ f_hi, unsigned short* __restrict__ f_lo,
    int* __restrict__ inv, unsigned* __restrict__ bar)
{
    int i = blockIdx.x * 256 + threadIdx.x;      // 262144 threads
    {
        int r  = i >> 5;
        int k0 = (i & 31) * 16;
        const float* srcp = features + (size_t)r * DIN + k0;
        __align__(16) unsigned short hv[16], lv[16];
        #pragma unroll
        for (int e = 0; e < 16; ++e) {
            float x = srcp[e];
            unsigned short h = f2bf(x);
            hv[e] = h;
            lv[e] = f2bf(x - bf2f(h));
        }
        int key = r & 7;
        int c0  = (k0 >> 3) & 7;
        size_t base = (size_t)r * KH + (k0 & ~63);
        *(uint4*)&f_hi[base + ((c0 ^ key) * 8)]       = *(const uint4*)&hv[0];
        *(uint4*)&f_hi[base + (((c0 + 1) ^ key) * 8)] = *(const uint4*)&hv[8];
        *(uint4*)&f_lo[base + ((c0 ^ key) * 8)]       = *(const uint4*)&lv[0];
        *(uint4*)&f_lo[base + (((c0 + 1) ^ key) * 8)] = *(const uint4*)&lv[8];
    }
    if (i < NNODES) inv[order[i]] = i;
    if (i < 256) bar[i] = 0u;
}

// ---------------------------------------------------------------------------
// prep_embed: g_embed[e][n''] = embed[e]·Wx[512:712][orig(n'')] + b[orig(n'')]
// ---------------------------------------------------------------------------
__global__ __launch_bounds__(128) void prep_embed(
    const float* __restrict__ embed, const float* __restrict__ Wx,
    const float* __restrict__ bvec, float* __restrict__ g_embed)
{
    int e    = blockIdx.y;
    int np   = blockIdx.x * 128 + threadIdx.x;
    int gate = (np >> 4) & 3, hcs = np >> 6, hcl = np & 15;
    int col  = gate * 512 + hcs * 16 + hcl;
    float acc = bvec[col];
    const float* er = embed + (size_t)e * ED;
    for (int k = 0; k < ED; ++k)
        acc += er[k] * Wx[(size_t)(DIN + k) * GDIM + col];
    g_embed[(size_t)e * GDIM + np] = acc;
}

// ===========================================================================
// forest_kernel: persistent kernel — all 16 levels in one launch.
// 512 blocks x 128 threads (2 blocks/CU).  Per level:
// phase G (gemm+cell) -> grid_barrier -> phase D (dist+argmax, 1 row/block)
// -> grid_barrier (skipped after last level).  Bodies identical to the
// round-5 829us kernels; only the sync mechanism changed (round-7 post-mortem:
// cg grid.sync ~85us/call = 2.7ms of the 3.2ms total).
// ===========================================================================
__global__ __launch_bounds__(128) void forest_kernel(
    float* h_all, float* c_all,
    const int* __restrict__ parent, int* __restrict__ cm_all,
    const unsigned short* __restrict__ w_hi, const unsigned short* __restrict__ w_lo,
    const unsigned short* __restrict__ f_hi, const unsigned short* __restrict__ f_lo,
    const float* __restrict__ g_embed, const float* __restrict__ dropout,
    const float* __restrict__ outW, const float* __restrict__ outb,
    const int* __restrict__ inv, float* __restrict__ d_out,
    unsigned* __restrict__ bar)
{
    __shared__ unsigned short Ah[32 * 64], Al[32 * 64], Bh[64 * 64], Bl[64 * 64];
    __shared__ int p_s[32], rt_s[32], ei_s[32];
    __shared__ float h_s[512];
    __shared__ float dist_s[160];

    const int t = threadIdx.x, w = t >> 6, lane = t & 63;
    const int bid = blockIdx.x;
    const int ns = bid & 31, mt = bid >> 5;

    for (int l = 0; l < DEPTH; ++l) {
        const int off = l * LEVEL_W;
        // ================= phase G: gemm + LSTM cell =================
        {
            const int grow0 = off + mt * 32;

            if (t < 32) {
                int p  = parent[grow0 + t];
                int rt = (p < 0) ? 1 : 0;
                p_s[t]  = rt ? 0 : p;
                rt_s[t] = rt;
                ei_s[t] = rt ? 0 : (cm_all[rt ? 0 : p] + 1);
            }
            __syncthreads();

            f4v acc[4];
            #pragma unroll
            for (int i = 0; i < 4; ++i) acc[i] = (f4v){0.f, 0.f, 0.f, 0.f};

            const int ar  = t >> 2;            // 0..31 (A gather row)
            const int aq  = t & 3;             // quarter of the 64-elem window
            const int ap  = p_s[ar];
            const int art = rt_s[ar];
            const float* asrc = h_all + (size_t)ap * HD + aq * 16;
            const int akey = ar & 7;
            const int ac0  = aq * 2;

            for (int kc = 0; kc < NKC; ++kc) {
                if (kc < 8) {
                    float x[16];
                    if (art) {
                        #pragma unroll
                        for (int e = 0; e < 16; ++e) x[e] = 0.f;
                    } else {
                        const float4* s4 = (const float4*)(asrc + kc * 64);
                        float4 v0 = s4[0], v1 = s4[1], v2 = s4[2], v3 = s4[3];
                        x[0] = v0.x; x[1] = v0.y; x[2] = v0.z; x[3] = v0.w;
                        x[4] = v1.x; x[5] = v1.y; x[6] = v1.z; x[7] = v1.w;
                        x[8] = v2.x; x[9] = v2.y; x[10] = v2.z; x[11] = v2.w;
                        x[12] = v3.x; x[13] = v3.y; x[14] = v3.z; x[15] = v3.w;
                    }
                    __align__(16) unsigned short hv[16], lv[16];
                    #pragma unroll
                    for (int e = 0; e < 16; ++e) {
                        unsigned short h = f2bf(x[e]);
                        hv[e] = h;
                        lv[e] = f2bf(x[e] - bf2f(h));
                    }
                    *(uint4*)&Ah[ar * 64 + ((ac0 ^ akey) * 8)]       = *(const uint4*)&hv[0];
                    *(uint4*)&Ah[ar * 64 + (((ac0 + 1) ^ akey) * 8)] = *(const uint4*)&hv[8];
                    *(uint4*)&Al[ar * 64 + ((ac0 ^ akey) * 8)]       = *(const uint4*)&lv[0];
                    *(uint4*)&Al[ar * 64 + (((ac0 + 1) ^ akey) * 8)] = *(const uint4*)&lv[8];
                } else {
                    #pragma unroll
                    for (int q = 0; q < 2; ++q) {
                        int ia  = w * 2 + q;                       // 0..3, wave-uniform
                        int row = ia * 8 + (lane >> 3);            // 0..31
                        size_t aoff = ((size_t)(grow0 + row) * KH + (kc - 8) * 64) * 2
                                      + (lane & 7) * 16;
                        gl_lds16((const char*)f_hi + aoff, (char*)Ah + ia * 1024);
                        gl_lds16((const char*)f_lo + aoff, (char*)Al + ia * 1024);
                    }
                }
                #pragma unroll
                for (int q = 0; q < 4; ++q) {
                    int ib  = w * 4 + q;                           // 0..7, wave-uniform
                    int row = ib * 8 + (lane >> 3);                // 0..63
                    size_t boff = ((size_t)(ns * 64 + row) * KW + kc * 64) * 2
                                  + (lane & 7) * 16;
                    gl_lds16((const char*)w_hi + boff, (char*)Bh + ib * 1024);
                    gl_lds16((const char*)w_lo + boff, (char*)Bl + ib * 1024);
                }
                __syncthreads();
                #pragma unroll
                for (int s = 0; s < 2; ++s) {
                    int arow = w * 16 + (lane & 15);
                    int ach  = s * 4 + (lane >> 4);
                    s8v ahv = *(const s8v*)&Ah[arow * 64 + ((ach ^ (arow & 7)) * 8)];
                    s8v alv = *(const s8v*)&Al[arow * 64 + ((ach ^ (arow & 7)) * 8)];
                    #pragma unroll
                    for (int fn = 0; fn < 4; ++fn) {
                        int brow = fn * 16 + (lane & 15);
                        s8v bhv = *(const s8v*)&Bh[brow * 64 + ((ach ^ (brow & 7)) * 8)];
                        s8v blv = *(const s8v*)&Bl[brow * 64 + ((ach ^ (brow & 7)) * 8)];
                        acc[fn] = __builtin_amdgcn_mfma_f32_16x16x32_bf16(ahv, bhv, acc[fn], 0, 0, 0);
                        acc[fn] = __builtin_amdgcn_mfma_f32_16x16x32_bf16(ahv, blv, acc[fn], 0, 0, 0);
                        acc[fn] = __builtin_amdgcn_mfma_f32_16x16x32_bf16(alv, bhv, acc[fn], 0, 0, 0);
                    }
                }
                __syncthreads();
            }

            const int hcl  = lane & 15;
            const int hcol = ns * 16 + hcl;
            const float dm = dropout[hcol];
            #pragma unroll
            for (int j = 0; j < 4; ++j) {
                int lr   = w * 16 + (lane >> 4) * 4 + j;
                int grow = grow0 + lr;
                const float* gep = g_embed + (size_t)ei_s[lr] * GDIM + ns * 64;
                float gi = acc[0][j] + gep[0 * 16 + hcl];
                float gf = acc[1][j] + gep[1 * 16 + hcl];
                float gg = acc[2][j] + gep[2 * 16 + hcl];
                float go = acc[3][j] + gep[3 * 16 + hcl];
                float cpar = rt_s[lr] ? 0.f : c_all[(size_t)p_s[lr] * HD + hcol];
                float c2 = sigm(gf) * cpar + sigm(gi) * tanhf(gg);
                float h2 = sigm(go) * tanhf(c2) * dm;
                c_all[(size_t)grow * HD + hcol] = c2;
                h_all[(size_t)grow * HD + hcol] = h2;
            }
        }
        grid_barrier(bar);

        // ================= phase D: dist + argmax (1 row per block) ==
        {
            const int grow = off + bid;
            const float* hrow = h_all + (size_t)grow * HD;
            *(float4*)&h_s[t * 4] = ((const float4*)hrow)[t];
            __syncthreads();

            const int j  = t;
            const int j2 = t + 128;
            if (j < NC) {
                float a = 0.f;
                #pragma unroll 8
                for (int k = 0; k < HD; ++k) a += h_s[k] * outW[k * NC + j];
                dist_s[j] = a + outb[j];
            }
            if (j2 < NC) {
                float a = 0.f;
                #pragma unroll 8
                for (int k = 0; k < HD; ++k) a += h_s[k] * outW[k * NC + j2];
                dist_s[j2] = a + outb[j2];
            }
            __syncthreads();

            const int orow = inv[grow];
            if (orow < OUTROWS) {
                if (j < NC)  d_out[(size_t)orow * NC + j]  = dist_s[j];
                if (j2 < NC) d_out[(size_t)orow * NC + j2] = dist_s[j2];
            }

            if (t < 64) {
                float best = -FLT_MAX;
                int   bidx = 0x7fffffff;
                for (int jj = t; jj < NC; jj += 64) {
                    float v = dist_s[jj];
                    if (v > best || (v == best && jj < bidx)) { best = v; bidx = jj; }
                }
                #pragma unroll
                for (int m = 32; m >= 1; m >>= 1) {
                    float ov = __shfl_xor(best, m);
                    int   oi = __shfl_xor(bidx, m);
                    if (ov > best || (ov == best && oi < bidx)) { best = ov; bidx = oi; }
                }
                if (t == 0) {
                    cm_all[grow] = bidx;
                    if (orow < OUTROWS) d_out[(size_t)OUTROWS * NC + orow] = (float)bidx;
                }
            }
            __syncthreads();
        }
        if (l != DEPTH - 1) grid_barrier(bar);
    }
}

// ---------------------------------------------------------------------------
// Fallback per-level kernels (round-5 proven, 829us path); used only if the
// cooperative launch is rejected.
// ---------------------------------------------------------------------------
__global__ __launch_bounds__(128) void gemm_h_cell(
    float* h_all, float* c_all,
    const int* __restrict__ parent, const int* __restrict__ cm_all,
    const unsigned short* __restrict__ w_hi, const unsigned short* __restrict__ w_lo,
    const unsigned short* __restrict__ f_hi, const unsigned short* __restrict__ f_lo,
    const float* __restrict__ g_embed, const float* __restrict__ dropout, int off)
{
    __shared__ unsigned short Ah[32 * 64], Al[32 * 64], Bh[64 * 64], Bl[64 * 64];
    __shared__ int p_s[32], rt_s[32], ei_s[32];
    const int t = threadIdx.x, w = t >> 6, lane = t & 63;
    const int ns = blockIdx.x, mt = blockIdx.y;
    const int grow0 = off + mt * 32;

    if (t < 32) {
        int p  = parent[grow0 + t];
        int rt = (p < 0) ? 1 : 0;
        p_s[t]  = rt ? 0 : p;
        rt_s[t] = rt;
        ei_s[t] = rt ? 0 : (cm_all[rt ? 0 : p] + 1);
    }
    __syncthreads();

    f4v acc[4];
    #pragma unroll
    for (int i = 0; i < 4; ++i) acc[i] = (f4v){0.f, 0.f, 0.f, 0.f};

    const int ar  = t >> 2;
    const int aq  = t & 3;
    const int ap  = p_s[ar];
    const int art = rt_s[ar];
    const float* asrc = h_all + (size_t)ap * HD + aq * 16;
    const int akey = ar & 7;
    const int ac0  = aq * 2;

    for (int kc = 0; kc < NKC; ++kc) {
        if (kc < 8) {
            float x[16];
            if (art) {
                #pragma unroll
                for (int e = 0; e < 16; ++e) x[e] = 0.f;
            } else {
                const float4* s4 = (const float4*)(asrc + kc * 64);
                float4 v0 = s4[0], v1 = s4[1], v2 = s4[2], v3 = s4[3];
                x[0] = v0.x; x[1] = v0.y; x[2] = v0.z; x[3] = v0.w;
                x[4] = v1.x; x[5] = v1.y; x[6] = v1.z; x[7] = v1.w;
                x[8] = v2.x; x[9] = v2.y; x[10] = v2.z; x[11] = v2.w;
                x[12] = v3.x; x[13] = v3.y; x[14] = v3.z; x[15] = v3.w;
            }
            __align__(16) unsigned short hv[16], lv[16];
            #pragma unroll
            for (int e = 0; e < 16; ++e) {
                unsigned short h = f2bf(x[e]);
                hv[e] = h;
                lv[e] = f2bf(x[e] - bf2f(h));
            }
            *(uint4*)&Ah[ar * 64 + ((ac0 ^ akey) * 8)]       = *(const uint4*)&hv[0];
            *(uint4*)&Ah[ar * 64 + (((ac0 + 1) ^ akey) * 8)] = *(const uint4*)&hv[8];
            *(uint4*)&Al[ar * 64 + ((ac0 ^ akey) * 8)]       = *(const uint4*)&lv[0];
            *(uint4*)&Al[ar * 64 + (((ac0 + 1) ^ akey) * 8)] = *(const uint4*)&lv[8];
        } else {
            #pragma unroll
            for (int q = 0; q < 2; ++q) {
                int ia  = w * 2 + q;
                int row = ia * 8 + (lane >> 3);
                size_t aoff = ((size_t)(grow0 + row) * KH + (kc - 8) * 64) * 2
                              + (lane & 7) * 16;
                gl_lds16((const char*)f_hi + aoff, (char*)Ah + ia * 1024);
                gl_lds16((const char*)f_lo + aoff, (char*)Al + ia * 1024);
            }
        }
        #pragma unroll
        for (int q = 0; q < 4; ++q) {
            int ib  = w * 4 + q;
            int row = ib * 8 + (lane >> 3);
            size_t boff = ((size_t)(ns * 64 + row) * KW + kc * 64) * 2
                          + (lane & 7) * 16;
            gl_lds16((const char*)w_hi + boff, (char*)Bh + ib * 1024);
            gl_lds16((const char*)w_lo + boff, (char*)Bl + ib * 1024);
        }
        __syncthreads();
        #pragma unroll
        for (int s = 0; s < 2; ++s) {
            int arow = w * 16 + (lane & 15);
            int ach  = s * 4 + (lane >> 4);
            s8v ahv = *(const s8v*)&Ah[arow * 64 + ((ach ^ (arow & 7)) * 8)];
            s8v alv = *(const s8v*)&Al[arow * 64 + ((ach ^ (arow & 7)) * 8)];
            #pragma unroll
            for (int fn = 0; fn < 4; ++fn) {
                int brow = fn * 16 + (lane & 15);
                s8v bhv = *(const s8v*)&Bh[brow * 64 + ((ach ^ (brow & 7)) * 8)];
                s8v blv = *(const s8v*)&Bl[brow * 64 + ((ach ^ (brow & 7)) * 8)];
                acc[fn] = __builtin_amdgcn_mfma_f32_16x16x32_bf16(ahv, bhv, acc[fn], 0, 0, 0);
                acc[fn] = __builtin_amdgcn_mfma_f32_16x16x32_bf16(ahv, blv, acc[fn], 0, 0, 0);
                acc[fn] = __builtin_amdgcn_mfma_f32_16x16x32_bf16(alv, bhv, acc[fn], 0, 0, 0);
            }
        }
        __syncthreads();
    }

    const int hcl  = lane & 15;
    const int hcol = ns * 16 + hcl;
    const float dm = dropout[hcol];
    #pragma unroll
    for (int j = 0; j < 4; ++j) {
        int lr   = w * 16 + (lane >> 4) * 4 + j;
        int grow = grow0 + lr;
        const float* gep = g_embed + (size_t)ei_s[lr] * GDIM + ns * 64;
        float gi = acc[0][j] + gep[0 * 16 + hcl];
        float gf = acc[1][j] + gep[1 * 16 + hcl];
        float gg = acc[2][j] + gep[2 * 16 + hcl];
        float go = acc[3][j] + gep[3 * 16 + hcl];
        float cpar = rt_s[lr] ? 0.f : c_all[(size_t)p_s[lr] * HD + hcol];
        float c2 = sigm(gf) * cpar + sigm(gi) * tanhf(gg);
        float h2 = sigm(go) * tanhf(c2) * dm;
        c_all[(size_t)grow * HD + hcol] = c2;
        h_all[(size_t)grow * HD + hcol] = h2;
    }
}

__global__ __launch_bounds__(256) void level_dist(
    const float* __restrict__ h_all, const float* __restrict__ outW,
    const float* __restrict__ outb, const int* __restrict__ inv,
    float* __restrict__ d_out, int* __restrict__ cm_all, int off)
{
    __shared__ float h_s[4][512];
    __shared__ float dist_s[4][160];

    const int tid = threadIdx.x;
    const int r0  = blockIdx.x * 4;

    for (int i4 = tid; i4 < 512; i4 += 256) {
        int row = i4 >> 7;
        int k   = (i4 & 127) * 4;
        *(float4*)&h_s[row][k] =
            *(const float4*)&h_all[(size_t)(off + r0 + row) * HD + k];
    }
    __syncthreads();

    const int j = tid;
    if (j < NC) {
        float a0 = 0.f, a1 = 0.f, a2 = 0.f, a3 = 0.f;
        for (int k = 0; k < HD; ++k) {
            float w = outW[k * NC + j];
            a0 += h_s[0][k] * w;
            a1 += h_s[1][k] * w;
            a2 += h_s[2][k] * w;
            a3 += h_s[3][k] * w;
        }
        float bj = outb[j];
        dist_s[0][j] = a0 + bj;
        dist_s[1][j] = a1 + bj;
        dist_s[2][j] = a2 + bj;
        dist_s[3][j] = a3 + bj;
    }
    __syncthreads();

    if (j < NC) {
        #pragma unroll
        for (int r = 0; r < 4; ++r) {
            int orow = inv[off + r0 + r];
            if (orow < OUTROWS) d_out[(size_t)orow * NC + j] = dist_s[r][j];
        }
    }

    const int r    = tid >> 6;
    const int lane = tid & 63;
    float best = -3.402823466e38f;
    int   bidx = 0x7fffffff;
    for (int jj = lane; jj < NC; jj += 64) {
        float v = dist_s[r][jj];
        if (v > best || (v == best && jj < bidx)) { best = v; bidx = jj; }
    }
    #pragma unroll
    for (int m = 32; m >= 1; m >>= 1) {
        float ov = __shfl_xor(best, m);
        int   oi = __shfl_xor(bidx, m);
        if (ov > best || (ov == best && oi < bidx)) { best = ov; bidx = oi; }
    }
    if (lane == 0) {
        int grow = off + r0 + r;
        cm_all[grow] = bidx;
        int orow = inv[grow];
        if (orow < OUTROWS) d_out[(size_t)OUTROWS * NC + orow] = (float)bidx;
    }
}

// ---------------------------------------------------------------------------
extern "C" void kernel_launch(void* const* d_in, const int* in_sizes, int n_in,
                              void* d_out, int out_size, void* d_ws, size_t ws_size,
                              hipStream_t stream)
{
    const float* features = (const float*)d_in[0];
    const float* embed    = (const float*)d_in[1];
    const float* Wx       = (const float*)d_in[2];
    const float* Wh       = (const float*)d_in[3];
    const float* bias     = (const float*)d_in[4];
    const float* outW     = (const float*)d_in[5];
    const float* outb     = (const float*)d_in[6];
    const float* dropout  = (const float*)d_in[7];
    const int*   parent   = (const int*)d_in[8];
    const int*   order    = (const int*)d_in[9];

    char* p = (char*)d_ws;
    unsigned short* w_hi   = (unsigned short*)p; p += (size_t)GDIM * KW * 2;   // 4MB
    unsigned short* w_lo   = (unsigned short*)p; p += (size_t)GDIM * KW * 2;   // 4MB
    unsigned short* f_hi   = (unsigned short*)p; p += (size_t)NNODES * KH * 2; // 8MB
    unsigned short* f_lo   = (unsigned short*)p; p += (size_t)NNODES * KH * 2; // 8MB
    float*          g_emb  = (float*)p;          p += (size_t)(NC + 2) * GDIM * 4;
    float*          h_all  = (float*)p;          p += (size_t)NNODES * HD * 4; // 16.8MB
    float*          c_all  = (float*)p;          p += (size_t)NNODES * HD * 4; // 16.8MB
    int*            cm_all = (int*)p;            p += (size_t)NNODES * 4;
    int*            inv    = (int*)p;            p += (size_t)NNODES * 4;
    unsigned*       bar    = (unsigned*)p;       p += 256 * sizeof(unsigned);

    float* out = (float*)d_out;

    prep_w<<<64, 256, 0, stream>>>(Wx, Wh, w_hi, w_lo);
    prep_feat<<<1024, 256, 0, stream>>>(features, order, f_hi, f_lo, inv, bar);
    prep_embed<<<dim3(16, NC + 1), 128, 0, stream>>>(embed, Wx, bias, g_emb);

    void* args[] = {
        (void*)&h_all, (void*)&c_all, (void*)&parent, (void*)&cm_all,
        (void*)&w_hi, (void*)&w_lo, (void*)&f_hi, (void*)&f_lo,
        (void*)&g_emb, (void*)&dropout, (void*)&outW, (void*)&outb,
        (void*)&inv, (void*)&out, (void*)&bar
    };
    hipError_t err = hipLaunchCooperativeKernel(
        (const void*)forest_kernel, dim3(NBLK), dim3(128), args, 0, stream);

    if (err != hipSuccess) {
        // Fallback: proven 32-launch path
        for (int l = 0; l < DEPTH; ++l) {
            int off = l * LEVEL_W;
            gemm_h_cell<<<dim3(32, 16), 128, 0, stream>>>(
                h_all, c_all, parent, cm_all, w_hi, w_lo, f_hi, f_lo, g_emb, dropout, off);
            level_dist<<<128, 256, 0, stream>>>(
                h_all, outW, outb, inv, out, cm_all, off);
        }
    }
}

// Round 9
// 1028.127 us; speedup vs baseline: 3.2233x; 2.3014x over previous
//
#include <hip/hip_runtime.h>
#include <math.h>
#include <float.h>

#define LEVEL_W 512
#define DEPTH   16
#define NNODES  8192
#define DIN     512
#define HD      512
#define ED      200
#define NC      150
#define GDIM    2048
#define OUTROWS 7680
#define KH      512        // f-buffer K (features), also h K
#define KW      1024       // combined weight K: [Wh(0:512) | Wx(512:1024)]
#define NKC     16         // K-chunks of 64 over KW
#define NBLK    512        // forest_kernel grid
#define BSUB    8          // barrier sub-counters

typedef __attribute__((ext_vector_type(8))) short s8v;   // 8 bf16 (4 VGPRs)
typedef __attribute__((ext_vector_type(4))) float f4v;   // 4 fp32 acc

__device__ __forceinline__ unsigned short f2bf(float x) {
    unsigned int u = __float_as_uint(x);
    u += 0x7FFFu + ((u >> 16) & 1u);
    return (unsigned short)(u >> 16);
}
__device__ __forceinline__ float bf2f(unsigned short b) {
    return __uint_as_float(((unsigned int)b) << 16);
}
__device__ __forceinline__ float sigm(float x) { return 1.0f / (1.0f + expf(-x)); }

__device__ __forceinline__ void gl_lds16(const void* g, void* l) {
    __builtin_amdgcn_global_load_lds((const __attribute__((address_space(1))) void*)g,
                                     (__attribute__((address_space(3))) void*)l, 16, 0, 0);
}

// Write-through (agent-scope) stores: land at the L3 coherence point so any
// XCD's first-touch cached read sees fresh data.  RELAXED => no L2 inv/wb ops.
__device__ __forceinline__ void st_wt(float* p, float v) {
    __hip_atomic_store(p, v, __ATOMIC_RELAXED, __HIP_MEMORY_SCOPE_AGENT);
}
__device__ __forceinline__ void st_wt_i(int* p, int v) {
    __hip_atomic_store(p, v, __ATOMIC_RELAXED, __HIP_MEMORY_SCOPE_AGENT);
}

// ---------------------------------------------------------------------------
// Hand-rolled grid barrier, v2 (round-8 post-mortem): round-8's ACQUIRE spin
// invalidated the XCD L2 on EVERY poll -> 174MB refetch/dispatch at 96GB/s.
// v2: ALL flag atomics RELAXED (no cache maintenance); ordering via explicit
// s_waitcnt vmcnt(0) (all cross-visible data stores are write-through, so
// vmcnt(0) completion == visible at L3).  Cross-block reads after the barrier
// are safe WITHOUT an acquire-invalidate because every such address is
// written exactly once, before its first read (structural coherence).
// Layout (unsigned units, 64B apart): sub[i]=bar[i*16], master=bar[128],
// gen=bar[144].  Zeroed by prep_feat each call.
// ---------------------------------------------------------------------------
__device__ __forceinline__ void grid_barrier(unsigned* bar) {
    __syncthreads();
    if (threadIdx.x == 0) {
        unsigned* sub    = bar + (blockIdx.x & (BSUB - 1)) * 16;
        unsigned* master = bar + BSUB * 16;
        unsigned* gen    = bar + (BSUB + 1) * 16;
        unsigned g = __hip_atomic_load(gen, __ATOMIC_RELAXED, __HIP_MEMORY_SCOPE_AGENT);
        asm volatile("s_waitcnt vmcnt(0)" ::: "memory");  // data stores -> L3
        unsigned v = __hip_atomic_fetch_add(sub, 1u, __ATOMIC_RELAXED, __HIP_MEMORY_SCOPE_AGENT);
        if (v == (NBLK / BSUB) - 1) {
            unsigned m = __hip_atomic_fetch_add(master, 1u, __ATOMIC_RELAXED, __HIP_MEMORY_SCOPE_AGENT);
            if (m == BSUB - 1) {
                #pragma unroll
                for (int i = 0; i < BSUB; ++i)
                    __hip_atomic_store(bar + i * 16, 0u, __ATOMIC_RELAXED, __HIP_MEMORY_SCOPE_AGENT);
                __hip_atomic_store(master, 0u, __ATOMIC_RELAXED, __HIP_MEMORY_SCOPE_AGENT);
                asm volatile("s_waitcnt vmcnt(0)" ::: "memory");  // resets before gen bump
                __hip_atomic_store(gen, g + 1u, __ATOMIC_RELEASE, __HIP_MEMORY_SCOPE_AGENT);
            }
        }
        while (__hip_atomic_load(gen, __ATOMIC_RELAXED, __HIP_MEMORY_SCOPE_AGENT) == g)
            __builtin_amdgcn_s_sleep(4);
        asm volatile("" ::: "memory");
    }
    __syncthreads();
}

// ---------------------------------------------------------------------------
// prep_w: combined W^T [2048 n''][1024 k] as bf16 hi/lo.
// n'' = hcs*64 + gate*16 + hcl  <->  orig col = gate*512 + hcs*16 + hcl.
// k 0..511 = Wh rows, k 512..1023 = Wx rows 0..511 (features part).
// 16B chunks XOR-swizzled within each 128B window (key = n'' & 7).
// ---------------------------------------------------------------------------
__global__ __launch_bounds__(256) void prep_w(
    const float* __restrict__ Wx, const float* __restrict__ Wh,
    unsigned short* __restrict__ w_hi, unsigned short* __restrict__ w_lo)
{
    __shared__ float Wt[64][65];
    const int t   = threadIdx.x;
    const int b   = blockIdx.x;
    const int mat = b >> 5;             // 0 = Wh (k 0..511), 1 = Wx (k 512..1023)
    const int ns  = b & 31;
    const float* src = mat ? Wx : Wh;

    for (int kw = 0; kw < 8; ++kw) {
        __syncthreads();
        #pragma unroll
        for (int p = 0; p < 16; ++p) {
            int gl  = p >> 2;
            int kk  = (p & 3) * 16 + (t >> 4);
            int col = gl * 512 + ns * 16 + (t & 15);
            Wt[kk][gl * 16 + (t & 15)] = src[(size_t)(kw * 64 + kk) * GDIM + col];
        }
        __syncthreads();
        {
            int nl  = t >> 2;
            int cp  = t & 3;
            int nsg = ns * 64 + nl;
            int key = nsg & 7;
            __align__(16) unsigned short hv[16], lv[16];
            #pragma unroll
            for (int e = 0; e < 16; ++e) {
                float x = Wt[cp * 16 + e][nl];
                unsigned short h = f2bf(x);
                hv[e] = h;
                lv[e] = f2bf(x - bf2f(h));
            }
            size_t base = (size_t)nsg * KW + mat * 512 + kw * 64;
            int c0 = cp * 2, c1 = cp * 2 + 1;
            *(uint4*)&w_hi[base + ((c0 ^ key) * 8)] = *(const uint4*)&hv[0];
            *(uint4*)&w_hi[base + ((c1 ^ key) * 8)] = *(const uint4*)&hv[8];
            *(uint4*)&w_lo[base + ((c0 ^ key) * 8)] = *(const uint4*)&lv[0];
            *(uint4*)&w_lo[base + ((c1 ^ key) * 8)] = *(const uint4*)&lv[8];
        }
    }
}

// ---------------------------------------------------------------------------
// prep_feat: features -> f_hi/f_lo bf16 [8192][512], chunk-swizzled (key r&7);
// inv[order[i]] = i; zero the barrier state.
// ---------------------------------------------------------------------------
__global__ __launch_bounds__(256) void prep_feat(
    const float* __restrict__ features, const int* __restrict__ order,
    unsigned short* __restrict__ f_hi, unsigned short* __restrict__ f_lo,
    int* __restrict__ inv, unsigned* __restrict__ bar)
{
    int i = blockIdx.x * 256 + threadIdx.x;      // 262144 threads
    {
        int r  = i >> 5;
        int k0 = (i & 31) * 16;
        const float* srcp = features + (size_t)r * DIN + k0;
        __align__(16) unsigned short hv[16], lv[16];
        #pragma unroll
        for (int e = 0; e < 16; ++e) {
            float x = srcp[e];
            unsigned short h = f2bf(x);
            hv[e] = h;
            lv[e] = f2bf(x - bf2f(h));
        }
        int key = r & 7;
        int c0  = (k0 >> 3) & 7;
        size_t base = (size_t)r * KH + (k0 & ~63);
        *(uint4*)&f_hi[base + ((c0 ^ key) * 8)]       = *(const uint4*)&hv[0];
        *(uint4*)&f_hi[base + (((c0 + 1) ^ key) * 8)] = *(const uint4*)&hv[8];
        *(uint4*)&f_lo[base + ((c0 ^ key) * 8)]       = *(const uint4*)&lv[0];
        *(uint4*)&f_lo[base + (((c0 + 1) ^ key) * 8)] = *(const uint4*)&lv[8];
    }
    if (i < NNODES) inv[order[i]] = i;
    if (i < 256) bar[i] = 0u;
}

// ---------------------------------------------------------------------------
// prep_embed: g_embed[e][n''] = embed[e]·Wx[512:712][orig(n'')] + b[orig(n'')]
// ---------------------------------------------------------------------------
__global__ __launch_bounds__(128) void prep_embed(
    const float* __restrict__ embed, const float* __restrict__ Wx,
    const float* __restrict__ bvec, float* __restrict__ g_embed)
{
    int e    = blockIdx.y;
    int np   = blockIdx.x * 128 + threadIdx.x;
    int gate = (np >> 4) & 3, hcs = np >> 6, hcl = np & 15;
    int col  = gate * 512 + hcs * 16 + hcl;
    float acc = bvec[col];
    const float* er = embed + (size_t)e * ED;
    for (int k = 0; k < ED; ++k)
        acc += er[k] * Wx[(size_t)(DIN + k) * GDIM + col];
    g_embed[(size_t)e * GDIM + np] = acc;
}

// ===========================================================================
// forest_kernel: persistent kernel — all 16 levels in one launch.
// 512 blocks x 128 threads (2 blocks/CU).  Per level:
// phase G (gemm+cell) -> grid_barrier -> phase D (dist+argmax, 1 row/block)
// -> grid_barrier.  All cross-block-visible writes are write-through
// (agent-scope relaxed atomics); cross-block reads are normal cached loads
// (each address written once, before first read => no stale copies can
// exist).  Weights/f/g_emb stay L2-resident across levels (no invalidation).
// ===========================================================================
__global__ __launch_bounds__(128) void forest_kernel(
    float* h_all, float* c_all,
    const int* __restrict__ parent, int* __restrict__ cm_all,
    const unsigned short* __restrict__ w_hi, const unsigned short* __restrict__ w_lo,
    const unsigned short* __restrict__ f_hi, const unsigned short* __restrict__ f_lo,
    const float* __restrict__ g_embed, const float* __restrict__ dropout,
    const float* __restrict__ outW, const float* __restrict__ outb,
    const int* __restrict__ inv, float* __restrict__ d_out,
    unsigned* __restrict__ bar)
{
    __shared__ unsigned short Ah[32 * 64], Al[32 * 64], Bh[64 * 64], Bl[64 * 64];
    __shared__ int p_s[32], rt_s[32], ei_s[32];
    __shared__ float h_s[512];
    __shared__ float dist_s[160];

    const int t = threadIdx.x, w = t >> 6, lane = t & 63;
    const int bid = blockIdx.x;
    const int ns = bid & 31, mt = bid >> 5;

    for (int l = 0; l < DEPTH; ++l) {
        const int off = l * LEVEL_W;
        // ================= phase G: gemm + LSTM cell =================
        {
            const int grow0 = off + mt * 32;

            if (t < 32) {
                int p  = parent[grow0 + t];
                int rt = (p < 0) ? 1 : 0;
                p_s[t]  = rt ? 0 : p;
                rt_s[t] = rt;
                ei_s[t] = rt ? 0 : (cm_all[rt ? 0 : p] + 1);
            }
            __syncthreads();

            f4v acc[4];
            #pragma unroll
            for (int i = 0; i < 4; ++i) acc[i] = (f4v){0.f, 0.f, 0.f, 0.f};

            const int ar  = t >> 2;            // 0..31 (A gather row)
            const int aq  = t & 3;             // quarter of the 64-elem window
            const int ap  = p_s[ar];
            const int art = rt_s[ar];
            const float* asrc = h_all + (size_t)ap * HD + aq * 16;
            const int akey = ar & 7;
            const int ac0  = aq * 2;

            for (int kc = 0; kc < NKC; ++kc) {
                if (kc < 8) {
                    float x[16];
                    if (art) {
                        #pragma unroll
                        for (int e = 0; e < 16; ++e) x[e] = 0.f;
                    } else {
                        const float4* s4 = (const float4*)(asrc + kc * 64);
                        float4 v0 = s4[0], v1 = s4[1], v2 = s4[2], v3 = s4[3];
                        x[0] = v0.x; x[1] = v0.y; x[2] = v0.z; x[3] = v0.w;
                        x[4] = v1.x; x[5] = v1.y; x[6] = v1.z; x[7] = v1.w;
                        x[8] = v2.x; x[9] = v2.y; x[10] = v2.z; x[11] = v2.w;
                        x[12] = v3.x; x[13] = v3.y; x[14] = v3.z; x[15] = v3.w;
                    }
                    __align__(16) unsigned short hv[16], lv[16];
                    #pragma unroll
                    for (int e = 0; e < 16; ++e) {
                        unsigned short h = f2bf(x[e]);
                        hv[e] = h;
                        lv[e] = f2bf(x[e] - bf2f(h));
                    }
                    *(uint4*)&Ah[ar * 64 + ((ac0 ^ akey) * 8)]       = *(const uint4*)&hv[0];
                    *(uint4*)&Ah[ar * 64 + (((ac0 + 1) ^ akey) * 8)] = *(const uint4*)&hv[8];
                    *(uint4*)&Al[ar * 64 + ((ac0 ^ akey) * 8)]       = *(const uint4*)&lv[0];
                    *(uint4*)&Al[ar * 64 + (((ac0 + 1) ^ akey) * 8)] = *(const uint4*)&lv[8];
                } else {
                    #pragma unroll
                    for (int q = 0; q < 2; ++q) {
                        int ia  = w * 2 + q;                       // 0..3, wave-uniform
                        int row = ia * 8 + (lane >> 3);            // 0..31
                        size_t aoff = ((size_t)(grow0 + row) * KH + (kc - 8) * 64) * 2
                                      + (lane & 7) * 16;
                        gl_lds16((const char*)f_hi + aoff, (char*)Ah + ia * 1024);
                        gl_lds16((const char*)f_lo + aoff, (char*)Al + ia * 1024);
                    }
                }
                #pragma unroll
                for (int q = 0; q < 4; ++q) {
                    int ib  = w * 4 + q;                           // 0..7, wave-uniform
                    int row = ib * 8 + (lane >> 3);                // 0..63
                    size_t boff = ((size_t)(ns * 64 + row) * KW + kc * 64) * 2
                                  + (lane & 7) * 16;
                    gl_lds16((const char*)w_hi + boff, (char*)Bh + ib * 1024);
                    gl_lds16((const char*)w_lo + boff, (char*)Bl + ib * 1024);
                }
                __syncthreads();
                #pragma unroll
                for (int s = 0; s < 2; ++s) {
                    int arow = w * 16 + (lane & 15);
                    int ach  = s * 4 + (lane >> 4);
                    s8v ahv = *(const s8v*)&Ah[arow * 64 + ((ach ^ (arow & 7)) * 8)];
                    s8v alv = *(const s8v*)&Al[arow * 64 + ((ach ^ (arow & 7)) * 8)];
                    #pragma unroll
                    for (int fn = 0; fn < 4; ++fn) {
                        int brow = fn * 16 + (lane & 15);
                        s8v bhv = *(const s8v*)&Bh[brow * 64 + ((ach ^ (brow & 7)) * 8)];
                        s8v blv = *(const s8v*)&Bl[brow * 64 + ((ach ^ (brow & 7)) * 8)];
                        acc[fn] = __builtin_amdgcn_mfma_f32_16x16x32_bf16(ahv, bhv, acc[fn], 0, 0, 0);
                        acc[fn] = __builtin_amdgcn_mfma_f32_16x16x32_bf16(ahv, blv, acc[fn], 0, 0, 0);
                        acc[fn] = __builtin_amdgcn_mfma_f32_16x16x32_bf16(alv, bhv, acc[fn], 0, 0, 0);
                    }
                }
                __syncthreads();
            }

            const int hcl  = lane & 15;
            const int hcol = ns * 16 + hcl;
            const float dm = dropout[hcol];
            #pragma unroll
            for (int j = 0; j < 4; ++j) {
                int lr   = w * 16 + (lane >> 4) * 4 + j;
                int grow = grow0 + lr;
                const float* gep = g_embed + (size_t)ei_s[lr] * GDIM + ns * 64;
                float gi = acc[0][j] + gep[0 * 16 + hcl];
                float gf = acc[1][j] + gep[1 * 16 + hcl];
                float gg = acc[2][j] + gep[2 * 16 + hcl];
                float go = acc[3][j] + gep[3 * 16 + hcl];
                float cpar = rt_s[lr] ? 0.f : c_all[(size_t)p_s[lr] * HD + hcol];
                float c2 = sigm(gf) * cpar + sigm(gi) * tanhf(gg);
                float h2 = sigm(go) * tanhf(c2) * dm;
                st_wt(&c_all[(size_t)grow * HD + hcol], c2);
                st_wt(&h_all[(size_t)grow * HD + hcol], h2);
            }
        }
        grid_barrier(bar);

        // ================= phase D: dist + argmax (1 row per block) ==
        {
            const int grow = off + bid;
            const float* hrow = h_all + (size_t)grow * HD;
            *(float4*)&h_s[t * 4] = ((const float4*)hrow)[t];
            __syncthreads();

            const int j  = t;
            const int j2 = t + 128;
            if (j < NC) {
                float a = 0.f;
                #pragma unroll 8
                for (int k = 0; k < HD; ++k) a += h_s[k] * outW[k * NC + j];
                dist_s[j] = a + outb[j];
            }
            if (j2 < NC) {
                float a = 0.f;
                #pragma unroll 8
                for (int k = 0; k < HD; ++k) a += h_s[k] * outW[k * NC + j2];
                dist_s[j2] = a + outb[j2];
            }
            __syncthreads();

            const int orow = inv[grow];
            if (orow < OUTROWS) {
                if (j < NC)  st_wt(&d_out[(size_t)orow * NC + j],  dist_s[j]);
                if (j2 < NC) st_wt(&d_out[(size_t)orow * NC + j2], dist_s[j2]);
            }

            if (t < 64) {
                float best = -FLT_MAX;
                int   bidx = 0x7fffffff;
                for (int jj = t; jj < NC; jj += 64) {
                    float v = dist_s[jj];
                    if (v > best || (v == best && jj < bidx)) { best = v; bidx = jj; }
                }
                #pragma unroll
                for (int m = 32; m >= 1; m >>= 1) {
                    float ov = __shfl_xor(best, m);
                    int   oi = __shfl_xor(bidx, m);
                    if (ov > best || (ov == best && oi < bidx)) { best = ov; bidx = oi; }
                }
                if (t == 0) {
                    st_wt_i(&cm_all[grow], bidx);
                    if (orow < OUTROWS) st_wt(&d_out[(size_t)OUTROWS * NC + orow], (float)bidx);
                }
            }
            __syncthreads();
        }
        if (l != DEPTH - 1) grid_barrier(bar);
    }
}

// ---------------------------------------------------------------------------
// Fallback per-level kernels (round-5 proven, 829us path); used only if the
// cooperative launch is rejected.
// ---------------------------------------------------------------------------
__global__ __launch_bounds__(128) void gemm_h_cell(
    float* h_all, float* c_all,
    const int* __restrict__ parent, const int* __restrict__ cm_all,
    const unsigned short* __restrict__ w_hi, const unsigned short* __restrict__ w_lo,
    const unsigned short* __restrict__ f_hi, const unsigned short* __restrict__ f_lo,
    const float* __restrict__ g_embed, const float* __restrict__ dropout, int off)
{
    __shared__ unsigned short Ah[32 * 64], Al[32 * 64], Bh[64 * 64], Bl[64 * 64];
    __shared__ int p_s[32], rt_s[32], ei_s[32];
    const int t = threadIdx.x, w = t >> 6, lane = t & 63;
    const int ns = blockIdx.x, mt = blockIdx.y;
    const int grow0 = off + mt * 32;

    if (t < 32) {
        int p  = parent[grow0 + t];
        int rt = (p < 0) ? 1 : 0;
        p_s[t]  = rt ? 0 : p;
        rt_s[t] = rt;
        ei_s[t] = rt ? 0 : (cm_all[rt ? 0 : p] + 1);
    }
    __syncthreads();

    f4v acc[4];
    #pragma unroll
    for (int i = 0; i < 4; ++i) acc[i] = (f4v){0.f, 0.f, 0.f, 0.f};

    const int ar  = t >> 2;
    const int aq  = t & 3;
    const int ap  = p_s[ar];
    const int art = rt_s[ar];
    const float* asrc = h_all + (size_t)ap * HD + aq * 16;
    const int akey = ar & 7;
    const int ac0  = aq * 2;

    for (int kc = 0; kc < NKC; ++kc) {
        if (kc < 8) {
            float x[16];
            if (art) {
                #pragma unroll
                for (int e = 0; e < 16; ++e) x[e] = 0.f;
            } else {
                const float4* s4 = (const float4*)(asrc + kc * 64);
                float4 v0 = s4[0], v1 = s4[1], v2 = s4[2], v3 = s4[3];
                x[0] = v0.x; x[1] = v0.y; x[2] = v0.z; x[3] = v0.w;
                x[4] = v1.x; x[5] = v1.y; x[6] = v1.z; x[7] = v1.w;
                x[8] = v2.x; x[9] = v2.y; x[10] = v2.z; x[11] = v2.w;
                x[12] = v3.x; x[13] = v3.y; x[14] = v3.z; x[15] = v3.w;
            }
            __align__(16) unsigned short hv[16], lv[16];
            #pragma unroll
            for (int e = 0; e < 16; ++e) {
                unsigned short h = f2bf(x[e]);
                hv[e] = h;
                lv[e] = f2bf(x[e] - bf2f(h));
            }
            *(uint4*)&Ah[ar * 64 + ((ac0 ^ akey) * 8)]       = *(const uint4*)&hv[0];
            *(uint4*)&Ah[ar * 64 + (((ac0 + 1) ^ akey) * 8)] = *(const uint4*)&hv[8];
            *(uint4*)&Al[ar * 64 + ((ac0 ^ akey) * 8)]       = *(const uint4*)&lv[0];
            *(uint4*)&Al[ar * 64 + (((ac0 + 1) ^ akey) * 8)] = *(const uint4*)&lv[8];
        } else {
            #pragma unroll
            for (int q = 0; q < 2; ++q) {
                int ia  = w * 2 + q;
                int row = ia * 8 + (lane >> 3);
                size_t aoff = ((size_t)(grow0 + row) * KH + (kc - 8) * 64) * 2
                              + (lane & 7) * 16;
                gl_lds16((const char*)f_hi + aoff, (char*)Ah + ia * 1024);
                gl_lds16((const char*)f_lo + aoff, (char*)Al + ia * 1024);
            }
        }
        #pragma unroll
        for (int q = 0; q < 4; ++q) {
            int ib  = w * 4 + q;
            int row = ib * 8 + (lane >> 3);
            size_t boff = ((size_t)(ns * 64 + row) * KW + kc * 64) * 2
                          + (lane & 7) * 16;
            gl_lds16((const char*)w_hi + boff, (char*)Bh + ib * 1024);
            gl_lds16((const char*)w_lo + boff, (char*)Bl + ib * 1024);
        }
        __syncthreads();
        #pragma unroll
        for (int s = 0; s < 2; ++s) {
            int arow = w * 16 + (lane & 15);
            int ach  = s * 4 + (lane >> 4);
            s8v ahv = *(const s8v*)&Ah[arow * 64 + ((ach ^ (arow & 7)) * 8)];
            s8v alv = *(const s8v*)&Al[arow * 64 + ((ach ^ (arow & 7)) * 8)];
            #pragma unroll
            for (int fn = 0; fn < 4; ++fn) {
                int brow = fn * 16 + (lane & 15);
                s8v bhv = *(const s8v*)&Bh[brow * 64 + ((ach ^ (brow & 7)) * 8)];
                s8v blv = *(const s8v*)&Bl[brow * 64 + ((ach ^ (brow & 7)) * 8)];
                acc[fn] = __builtin_amdgcn_mfma_f32_16x16x32_bf16(ahv, bhv, acc[fn], 0, 0, 0);
                acc[fn] = __builtin_amdgcn_mfma_f32_16x16x32_bf16(ahv, blv, acc[fn], 0, 0, 0);
                acc[fn] = __builtin_amdgcn_mfma_f32_16x16x32_bf16(alv, bhv, acc[fn], 0, 0, 0);
            }
        }
        __syncthreads();
    }

    const int hcl  = lane & 15;
    const int hcol = ns * 16 + hcl;
    const float dm = dropout[hcol];
    #pragma unroll
    for (int j = 0; j < 4; ++j) {
        int lr   = w * 16 + (lane >> 4) * 4 + j;
        int grow = grow0 + lr;
        const float* gep = g_embed + (size_t)ei_s[lr] * GDIM + ns * 64;
        float gi = acc[0][j] + gep[0 * 16 + hcl];
        float gf = acc[1][j] + gep[1 * 16 + hcl];
        float gg = acc[2][j] + gep[2 * 16 + hcl];
        float go = acc[3][j] + gep[3 * 16 + hcl];
        float cpar = rt_s[lr] ? 0.f : c_all[(size_t)p_s[lr] * HD + hcol];
        float c2 = sigm(gf) * cpar + sigm(gi) * tanhf(gg);
        float h2 = sigm(go) * tanhf(c2) * dm;
        c_all[(size_t)grow * HD + hcol] = c2;
        h_all[(size_t)grow * HD + hcol] = h2;
    }
}

__global__ __launch_bounds__(256) void level_dist(
    const float* __restrict__ h_all, const float* __restrict__ outW,
    const float* __restrict__ outb, const int* __restrict__ inv,
    float* __restrict__ d_out, int* __restrict__ cm_all, int off)
{
    __shared__ float h_s[4][512];
    __shared__ float dist_s[4][160];

    const int tid = threadIdx.x;
    const int r0  = blockIdx.x * 4;

    for (int i4 = tid; i4 < 512; i4 += 256) {
        int row = i4 >> 7;
        int k   = (i4 & 127) * 4;
        *(float4*)&h_s[row][k] =
            *(const float4*)&h_all[(size_t)(off + r0 + row) * HD + k];
    }
    __syncthreads();

    const int j = tid;
    if (j < NC) {
        float a0 = 0.f, a1 = 0.f, a2 = 0.f, a3 = 0.f;
        for (int k = 0; k < HD; ++k) {
            float w = outW[k * NC + j];
            a0 += h_s[0][k] * w;
            a1 += h_s[1][k] * w;
            a2 += h_s[2][k] * w;
            a3 += h_s[3][k] * w;
        }
        float bj = outb[j];
        dist_s[0][j] = a0 + bj;
        dist_s[1][j] = a1 + bj;
        dist_s[2][j] = a2 + bj;
        dist_s[3][j] = a3 + bj;
    }
    __syncthreads();

    if (j < NC) {
        #pragma unroll
        for (int r = 0; r < 4; ++r) {
            int orow = inv[off + r0 + r];
            if (orow < OUTROWS) d_out[(size_t)orow * NC + j] = dist_s[r][j];
        }
    }

    const int r    = tid >> 6;
    const int lane = tid & 63;
    float best = -3.402823466e38f;
    int   bidx = 0x7fffffff;
    for (int jj = lane; jj < NC; jj += 64) {
        float v = dist_s[r][jj];
        if (v > best || (v == best && jj < bidx)) { best = v; bidx = jj; }
    }
    #pragma unroll
    for (int m = 32; m >= 1; m >>= 1) {
        float ov = __shfl_xor(best, m);
        int   oi = __shfl_xor(bidx, m);
        if (ov > best || (ov == best && oi < bidx)) { best = ov; bidx = oi; }
    }
    if (lane == 0) {
        int grow = off + r0 + r;
        cm_all[grow] = bidx;
        int orow = inv[grow];
        if (orow < OUTROWS) d_out[(size_t)OUTROWS * NC + orow] = (float)bidx;
    }
}

// ---------------------------------------------------------------------------
extern "C" void kernel_launch(void* const* d_in, const int* in_sizes, int n_in,
                              void* d_out, int out_size, void* d_ws, size_t ws_size,
                              hipStream_t stream)
{
    const float* features = (const float*)d_in[0];
    const float* embed    = (const float*)d_in[1];
    const float* Wx       = (const float*)d_in[2];
    const float* Wh       = (const float*)d_in[3];
    const float* bias     = (const float*)d_in[4];
    const float* outW     = (const float*)d_in[5];
    const float* outb     = (const float*)d_in[6];
    const float* dropout  = (const float*)d_in[7];
    const int*   parent   = (const int*)d_in[8];
    const int*   order    = (const int*)d_in[9];

    char* p = (char*)d_ws;
    unsigned short* w_hi   = (unsigned short*)p; p += (size_t)GDIM * KW * 2;   // 4MB
    unsigned short* w_lo   = (unsigned short*)p; p += (size_t)GDIM * KW * 2;   // 4MB
    unsigned short* f_hi   = (unsigned short*)p; p += (size_t)NNODES * KH * 2; // 8MB
    unsigned short* f_lo   = (unsigned short*)p; p += (size_t)NNODES * KH * 2; // 8MB
    float*          g_emb  = (float*)p;          p += (size_t)(NC + 2) * GDIM * 4;
    float*          h_all  = (float*)p;          p += (size_t)NNODES * HD * 4; // 16.8MB
    float*          c_all  = (float*)p;          p += (size_t)NNODES * HD * 4; // 16.8MB
    int*            cm_all = (int*)p;            p += (size_t)NNODES * 4;
    int*            inv    = (int*)p;            p += (size_t)NNODES * 4;
    unsigned*       bar    = (unsigned*)p;       p += 256 * sizeof(unsigned);

    float* out = (float*)d_out;

    prep_w<<<64, 256, 0, stream>>>(Wx, Wh, w_hi, w_lo);
    prep_feat<<<1024, 256, 0, stream>>>(features, order, f_hi, f_lo, inv, bar);
    prep_embed<<<dim3(16, NC + 1), 128, 0, stream>>>(embed, Wx, bias, g_emb);

    void* args[] = {
        (void*)&h_all, (void*)&c_all, (void*)&parent, (void*)&cm_all,
        (void*)&w_hi, (void*)&w_lo, (void*)&f_hi, (void*)&f_lo,
        (void*)&g_emb, (void*)&dropout, (void*)&outW, (void*)&outb,
        (void*)&inv, (void*)&out, (void*)&bar
    };
    hipError_t err = hipLaunchCooperativeKernel(
        (const void*)forest_kernel, dim3(NBLK), dim3(128), args, 0, stream);

    if (err != hipSuccess) {
        // Fallback: proven 32-launch path
        for (int l = 0; l < DEPTH; ++l) {
            int off = l * LEVEL_W;
            gemm_h_cell<<<dim3(32, 16), 128, 0, stream>>>(
                h_all, c_all, parent, cm_all, w_hi, w_lo, f_hi, f_lo, g_emb, dropout, off);
            level_dist<<<128, 256, 0, stream>>>(
                h_all, outW, outb, inv, out, cm_all, off);
        }
    }
}